// Round 13
// baseline (377.804 us; speedup 1.0000x reference)
//
#include <hip/hip_runtime.h>
#include <stdint.h>

typedef unsigned int u32;
typedef unsigned long long u64;

#define HH 256
#define WW 512
#define HW (HH*WW)          // 131072
#define N2 (2*HW)           // 262144 per branch
#define NT (2*N2)           // 524288 total boxes
#define TOPK 4096
#define SCORE_THR 0.2f
#define NMS_THR 0.15f

// ---- workspace layout (bytes) ----
// [0, 2MB)  keys -> reused as NMS mask (4096*64 u64 = 2 MB exactly)
#define OFF_KEYS   0ull
#define OFF_GHIST  ((size_t)NT*4)                  // u32[1024] = 4 KB @ 2,097,152
#define OFF_GHIST2 (OFF_GHIST + 4096)              // u32[1024] = 4 KB
#define OFF_CNT    (OFF_GHIST2 + 4096)             // u32 (+pad 16)
#define OFF_VALIDM (OFF_CNT + 16)                  // u64[64] = 512 B
#define OFF_CAND   (OFF_VALIDM + 512)              // u64[8192] = 64 KB
#define OFF_STAND  OFF_CAND                        // float4[4096] overlays cand
#define OFF_SELIDX (OFF_CAND + 65536)              // u32[4096]
#define OFF_SELSC  (OFF_SELIDX + (size_t)TOPK*4)   // f32[4096]
#define OFF_TDIAG  (OFF_SELSC + (size_t)TOPK*4)    // u64[4096] = 32 KB
// end = 2,236,944 B < 2,261,008 proven in R6/R8
#define ZERO_BYTES (4096 + 4096 + 16)              // ghist + ghist2 + cnt

// orderable key for float (descending sortable as unsigned)
__device__ __forceinline__ u32 f2ord(float f) {
    u32 b = __float_as_uint(f);
    return (b & 0x80000000u) ? ~b : (b | 0x80000000u);
}

// ---------------- K1: scores -> keys + per-block LDS hist1 -> global -------
// Proven R9/R11 structure. Two-level 10+10-bit selection: level-2 bins span
// 2^12 ulps (~2.4e-4 in value) -> cut-bin population ~36 << slack. (R12's
// single-level 12-bit failed: bins span 0.0625 -> ~9300 > 4096 slack.)
__global__ void __launch_bounds__(1024) k_keys(const float* __restrict__ psm_v,
                                               const float* __restrict__ psm_i,
                                               u32* __restrict__ keys,
                                               u32* __restrict__ ghist) {
    __shared__ u32 lh[1024];
    int t = threadIdx.x;
    lh[t] = 0;
    __syncthreads();
    int n = blockIdx.x * 1024 + t;
    int br = n >> 18;
    int m  = n & (N2 - 1);
    int a  = m & 1;
    int hw = m >> 1;
    const float* psm = br ? psm_i : psm_v;
    float x = psm[a * HW + hw];
    float s = 1.0f / (1.0f + __builtin_expf(-x));   // mirror ref f32 sigmoid
    u32 key = 0u;
    if (s > SCORE_THR) key = f2ord(s);
    keys[n] = key;
    if (key) atomicAdd(&lh[key >> 22], 1u);
    __syncthreads();
    u32 c = lh[t];
    if (c) atomicAdd(&ghist[t], c);
}

// Wave-0 suffix-scan pivot over a 1024-entry count array (16 entries/lane).
// suffix(b) non-increasing -> unique crossing (lane,j) writes result (race-free).
__device__ __forceinline__ void pivot1024(const u32* __restrict__ arr, u32 target,
                                          u32* out_bin, u32* out_next, int l) {
    u32 h[16], loc[16];
#pragma unroll
    for (int j = 0; j < 16; ++j) h[j] = arr[l * 16 + j];
    loc[15] = h[15];
#pragma unroll
    for (int j = 14; j >= 0; --j) loc[j] = loc[j + 1] + h[j];
    u32 T = loc[0];
    u32 incl = T;
#pragma unroll
    for (int d = 1; d < 64; d <<= 1) {
        u32 v = __shfl_down(incl, d);
        if (l + d < 64) incl += v;
    }
    u32 E = incl - T;                      // sum over lanes > l
#pragma unroll
    for (int j = 0; j < 16; ++j) {
        u32 S  = loc[j] + E;
        u32 Sn = (j < 15 ? loc[j + 1] : 0u) + E;
        if (S >= target && Sn < target) {
            *out_bin = (u32)(l * 16 + j);
            *out_next = Sn;
        }
    }
}

// ---------------- K2: hist2 over key>>12 within pivot-1 bin (512 blocks) ----
__global__ void __launch_bounds__(1024) k_hist2(const u32* __restrict__ ghist,
                                                const u32* __restrict__ keys,
                                                u32* __restrict__ ghist2) {
    __shared__ u32 lh[1024];
    __shared__ u32 b1_sh;
    int tid = threadIdx.x;
    lh[tid] = 0;
    if (tid < 64) {
        u32 bin = 0xFFFFFFFFu, nxt = 0;
        pivot1024(ghist, (u32)TOPK, &bin, &nxt, tid);
        if (bin != 0xFFFFFFFFu) b1_sh = bin;    // winner-lane writes
    }
    __syncthreads();
    u32 b1 = b1_sh;
    int n = blockIdx.x * 1024 + tid;
    u32 key = keys[n];
    if ((key >> 22) == b1) atomicAdd(&lh[(key >> 12) & 1023u], 1u);
    __syncthreads();
    u32 c = lh[tid];
    if (c) atomicAdd(&ghist2[tid], c);
}

// ---------------- K3: compact at 20-bit cut (512 blocks) --------------------
__global__ void __launch_bounds__(1024) k_collect(const u32* __restrict__ ghist,
                                                  const u32* __restrict__ ghist2,
                                                  const u32* __restrict__ keys,
                                                  u64* __restrict__ cand,
                                                  u32* __restrict__ cnt) {
    __shared__ u32 b1_sh, t2_sh, b2_sh;
    int tid = threadIdx.x;
    if (tid < 64) {
        u32 bin = 0xFFFFFFFFu, nxt = 0;
        pivot1024(ghist, (u32)TOPK, &bin, &nxt, tid);
        if (bin != 0xFFFFFFFFu) { b1_sh = bin; t2_sh = (u32)TOPK - nxt; }
    }
    __syncthreads();
    if (tid < 64) {
        u32 bin = 0xFFFFFFFFu, nxt = 0;
        pivot1024(ghist2, t2_sh, &bin, &nxt, tid);
        if (bin != 0xFFFFFFFFu) b2_sh = bin;
    }
    __syncthreads();
    u32 thr20 = (b1_sh << 10) | b2_sh;
    int n = blockIdx.x * 1024 + tid;
    u32 key = keys[n];
    if ((key >> 12) >= thr20) {
        u32 pos = atomicAdd(cnt, 1u);
        if (pos < 8192u)
            cand[pos] = ((u64)key << 32) | (u64)(u32)(~(u32)n);
    }
}

// ---------------- K4: rank-by-counting selection ----------------------------
__global__ void __launch_bounds__(256) k_rank(const u64* __restrict__ cand,
                                              const u32* __restrict__ cnt,
                                              u32* __restrict__ sel_idx) {
    __shared__ u64 tile[1024];
    int tid = threadIdx.x;
    int i = blockIdx.x * 256 + tid;
    u32 c = *cnt;
    if (c > 8192u) c = 8192u;
    u64 my = (i < (int)c) ? cand[i] : 0ull;
    u32 rank = 0;
    for (u32 base = 0; base < c; base += 1024) {
#pragma unroll
        for (int k = 0; k < 4; ++k) {
            u32 idx = base + tid + k * 256;
            tile[tid + k * 256] = (idx < c) ? cand[idx] : 0ull;
        }
        __syncthreads();
        u32 lim = (c - base < 1024u) ? (c - base) : 1024u;
#pragma unroll 4
        for (u32 k = 0; k < lim; ++k) rank += (tile[k] > my) ? 1u : 0u;
        __syncthreads();
    }
    if (i < (int)c && rank < (u32)TOPK)
        sel_idx[rank] = ~((u32)(my & 0xFFFFFFFFull));
}

// ---------------- box math helpers (mirror the jax reference) ---------------
__device__ __forceinline__ void box_corners(const float b[7], float cx[8], float cy[8], float cz[8]) {
    const float sx[8] = {0.5f,0.5f,-0.5f,-0.5f,0.5f,0.5f,-0.5f,-0.5f};
    const float sy[8] = {0.5f,-0.5f,-0.5f,0.5f,0.5f,-0.5f,-0.5f,0.5f};
    const float sz[8] = {-0.5f,-0.5f,-0.5f,-0.5f,0.5f,0.5f,0.5f,0.5f};
    float c = __builtin_cosf(b[6]), s = __builtin_sinf(b[6]);
#pragma unroll
    for (int k = 0; k < 8; k++) {
        float x = b[5] * sx[k], y = b[4] * sy[k], z = b[3] * sz[k];
        cx[k] = x * c - y * s + b[0];
        cy[k] = x * s + y * c + b[1];
        cz[k] = z + b[2];
    }
}

__device__ __forceinline__ void proj_T(const float* __restrict__ T, float cx[8], float cy[8], float cz[8]) {
#pragma unroll
    for (int k = 0; k < 8; k++) {
        float x = cx[k], y = cy[k], z = cz[k];
        cx[k] = T[0] * x + T[1] * y + T[2]  * z + T[3];
        cy[k] = T[4] * x + T[5] * y + T[6]  * z + T[7];
        cz[k] = T[8] * x + T[9] * y + T[10] * z + T[11];
    }
}

__device__ __forceinline__ void corner_to_center(const float cx[8], const float cy[8], const float cz[8], float b[7]) {
    float mx = 0.f, my = 0.f, mz = 0.f;
#pragma unroll
    for (int k = 0; k < 8; k++) { mx += cx[k]; my += cy[k]; mz += cz[k]; }
    mx *= 0.125f; my *= 0.125f; mz *= 0.125f;
    float htop = (cz[4] + cz[5] + cz[6] + cz[7]) * 0.25f;
    float hbot = (cz[0] + cz[1] + cz[2] + cz[3]) * 0.25f;
    const int lA[4] = {0,1,4,5}, lB[4] = {3,2,7,6};
    const int wA[4] = {0,3,4,7}, wB[4] = {1,2,5,6};
    float l = 0.f, w = 0.f, dx = 0.f, dy = 0.f;
#pragma unroll
    for (int i = 0; i < 4; i++) {
        float ax = cx[lA[i]] - cx[lB[i]];
        float ay = cy[lA[i]] - cy[lB[i]];
        l += __builtin_sqrtf(ax * ax + ay * ay);
        dx += ax; dy += ay;
    }
#pragma unroll
    for (int i = 0; i < 4; i++) {
        float ax = cx[wA[i]] - cx[wB[i]];
        float ay = cy[wA[i]] - cy[wB[i]];
        w += __builtin_sqrtf(ax * ax + ay * ay);
    }
    b[0] = mx; b[1] = my; b[2] = mz;
    b[3] = htop - hbot;
    b[4] = w * 0.25f;
    b[5] = l * 0.25f;
    b[6] = atan2f(dy, dx);
}

// ---------------- K5: decode boxes -> out corners + standup + validm --------
__global__ void __launch_bounds__(256) k_boxes(const float* __restrict__ anchors,
                                               const float* __restrict__ psm_v,
                                               const float* __restrict__ psm_i,
                                               const float* __restrict__ rm_v,
                                               const float* __restrict__ rm_i,
                                               const float* __restrict__ tproj,
                                               const float* __restrict__ tego,
                                               const u32* __restrict__ sel_idx,
                                               float* __restrict__ sel_sc,
                                               float* __restrict__ out,
                                               float4* __restrict__ stand,
                                               u64* __restrict__ validm) {
    int k = blockIdx.x * blockDim.x + threadIdx.x;
    if (k >= TOPK) return;
    int n = (int)(sel_idx[k] & (u32)(NT - 1));
    int br = n >> 18;
    int m  = n & (N2 - 1);
    int a  = m & 1;
    int hw = m >> 1;

    const float* psm = br ? psm_i : psm_v;
    float xs = psm[a * HW + hw];
    float s  = 1.0f / (1.0f + __builtin_expf(-xs));
    sel_sc[k] = (s > SCORE_THR) ? s : -1.0f;
    u64 vbits = __ballot(s > SCORE_THR);
    if ((threadIdx.x & 63) == 0) validm[k >> 6] = vbits;   // one word per wave

    const float* rm = br ? rm_i : rm_v;
    float d[7];
#pragma unroll
    for (int j = 0; j < 7; j++) d[j] = rm[(a * 7 + j) * HW + hw];
    const float* anc = anchors + (size_t)m * 7;
    float a0 = anc[0], a1 = anc[1], a2 = anc[2], a3 = anc[3], a4 = anc[4], a5 = anc[5], a6 = anc[6];
    float ad = __builtin_sqrtf(a4 * a4 + a5 * a5);
    float b[7];
    b[0] = d[0] * ad + a0;
    b[1] = d[1] * ad + a1;
    b[2] = d[2] * a3 + a2;
    b[3] = __builtin_expf(d[3]) * a3;
    b[4] = __builtin_expf(d[4]) * a4;
    b[5] = __builtin_expf(d[5]) * a5;
    b[6] = d[6] + a6;

    if (br) {  // infrared branch: corners -> t_proj -> back to center form
        float cx[8], cy[8], cz[8];
        box_corners(b, cx, cy, cz);
        proj_T(tproj, cx, cy, cz);
        corner_to_center(cx, cy, cz, b);
    }

    float cx[8], cy[8], cz[8];
    box_corners(b, cx, cy, cz);
    proj_T(tego, cx, cy, cz);

    float mnx = cx[0], mny = cy[0], mxx = cx[0], mxy = cy[0];
#pragma unroll
    for (int c = 0; c < 8; c++) {
        out[(size_t)k * 25 + c * 3 + 0] = cx[c];
        out[(size_t)k * 25 + c * 3 + 1] = cy[c];
        out[(size_t)k * 25 + c * 3 + 2] = cz[c];
        mnx = fminf(mnx, cx[c]); mny = fminf(mny, cy[c]);
        mxx = fmaxf(mxx, cx[c]); mxy = fmaxf(mxy, cy[c]);
    }
    stand[k] = make_float4(mnx, mny, mxx, mxy);
}

// ---------------- K6: suppression bitmask + fused transposed-diag -----------
// Blocks <1024: row bitmask (4 rows/block). Blocks 1024..1039: wave w
// computes tdiag for chunk (bid-1024)*4+w; stand reads uniform -> scalar.
// IoU expression order matches the row path (fmaxf/fminf symmetric, same
// area-sum order) -> bit-identical decisions.
__global__ void __launch_bounds__(256) k_mask(const float4* __restrict__ stand,
                                              u64* __restrict__ mask,
                                              u64* __restrict__ tdiag) {
    int bid = blockIdx.x;
    if (bid < 1024) {
        int i = bid * 4 + (threadIdx.x >> 6);
        int t = threadIdx.x & 63;
        int w0 = i >> 6;                    // chunks below diagonal are all-zero
        float4 bi = stand[i];
        float areai = (bi.z - bi.x) * (bi.w - bi.y);
        u64 myword = 0ull;
        for (int w = w0; w < 64; ++w) {
            int j = w * 64 + t;
            float4 bj = stand[j];
            float areaj = (bj.z - bj.x) * (bj.w - bj.y);
            float ltx = fmaxf(bi.x, bj.x), lty = fmaxf(bi.y, bj.y);
            float rbx = fminf(bi.z, bj.z), rby = fminf(bi.w, bj.w);
            float iw = fmaxf(rbx - ltx, 0.0f), ih = fmaxf(rby - lty, 0.0f);
            float inter = iw * ih;
            float iou = inter / (areai + areaj - inter + 1e-6f);
            bool sup = (iou > NMS_THR) && (j > i);
            u64 bits = __ballot(sup);
            if (t == w) myword = bits;
        }
        mask[(size_t)i * 64 + t] = myword;
    } else {
        int D = (bid - 1024) * 4 + (threadIdx.x >> 6);
        int l = threadIdx.x & 63;
        float4 me = stand[D * 64 + l];
        float aream = (me.z - me.x) * (me.w - me.y);
        u64 T = 0ull;
        for (int j = 0; j < 64; ++j) {
            float4 bj = stand[D * 64 + j];           // uniform -> scalar load
            float areaj = (bj.z - bj.x) * (bj.w - bj.y);
            float ltx = fmaxf(bj.x, me.x), lty = fmaxf(bj.y, me.y);
            float rbx = fminf(bj.z, me.z), rby = fminf(bj.w, me.w);
            float iw = fmaxf(rbx - ltx, 0.0f), ih = fmaxf(rby - lty, 0.0f);
            float inter = iw * ih;
            float iou = inter / (areaj + aream - inter + 1e-6f);
            bool sup = (iou > NMS_THR) && (j < l);
            T |= sup ? (1ull << j) : 0ull;
        }
        tdiag[D * 64 + l] = T;
    }
}

// ---------------- K7: single-wave NMS, upper-triangle DMA + fixpoint --------
// Chunk B's fold only feeds remv columns > B (word B is consumed by chain(B)
// BEFORE fold(B); columns < B never read again), so only words >= (B+1)&~1
// are staged: 1.05 MB vs 2 MB. Coverage invariant: fold(B') covers word C for
// all B'<C since (B'+1)&~1 <= C. Magic-divide exact for HN<=31, u<1984.
__global__ void __launch_bounds__(64) k_nms(const u64* __restrict__ mask,
                                            const u64* __restrict__ tdiag,
                                            const u64* __restrict__ validm,
                                            const float* __restrict__ sc,
                                            float* __restrict__ out) {
    __shared__ u64 buf[2][4096];   // ping-pong, 32 KB each max (W<=64)
    int l = threadIdx.x;
    u64 remv = 0ull;   // lane l: suppression word l
    u64 keep = 0ull;   // lane l: keep word of chunk l
    // prologue: stage chunk 0 full-width (Ws=0, W=64 -> row=u>>5, pair=u&31)
#pragma unroll
    for (int j = 0; j < 32; ++j) {
        int u = j * 64 + l;
        int row = u >> 5, pair = u & 31;
        const u64* g = mask + (size_t)row * 64 + pair * 2;
        __builtin_amdgcn_global_load_lds(
            (const __attribute__((address_space(1))) void*)g,
            (__attribute__((address_space(3))) void*)&buf[0][(size_t)j * 128], 16, 0, 0);
    }
    __builtin_amdgcn_s_waitcnt(0x0F70);   // vmcnt(0)
    asm volatile("" ::: "memory");
    for (int B = 0; B < 64; ++B) {
        int cur = B & 1;
        // stage chunk B+1's triangle into the other half
        if (B < 63) {
            u32 WsN = (u32)(B + 2) & ~1u;
            u32 HN  = (64u - WsN) >> 1;            // 16B pairs per row
            if (HN) {
                u32 M = 65535u / HN + 1u;          // exact magic for n<2048
                const u64* gb = mask + (size_t)(B + 1) * 4096 + WsN;
                for (u32 j = 0; j < HN; ++j) {
                    u32 u = j * 64u + (u32)l;
                    u32 row = (u * M) >> 16;
                    u32 pair = u - row * HN;
                    const u64* g = gb + (size_t)row * 64 + pair * 2;
                    __builtin_amdgcn_global_load_lds(
                        (const __attribute__((address_space(1))) void*)g,
                        (__attribute__((address_space(3))) void*)&buf[cur ^ 1][(size_t)j * 128],
                        16, 0, 0);
                }
            }
        }
        // ---- chain: fixpoint on precomputed transposed words (R11-proven) --
        u64 Tl = tdiag[B * 64 + l];
        u64 vm = validm[B];
        u64 curw = (((u64)(u32)__builtin_amdgcn_readlane((int)(u32)(remv >> 32), B)) << 32)
                 |   (u64)(u32)__builtin_amdgcn_readlane((int)(u32)remv, B);
        u64 ve = vm & ~curw;
        u64 D = 0ull, P = ve;
        while (D != P) {
            u64 nD = ve & ~__ballot((Tl & P) != 0ull);
            u64 nP = ve & ~__ballot((Tl & nD) != 0ull);
            D = nD; P = nP;
        }
        u64 kb = D;
        keep = (l == B) ? kb : keep;
        // ---- fold chunk B's kept rows (packed width-W rows in buf[cur]) ----
        u32 Ws = (u32)(B + 1) & ~1u;
        u32 W  = 64u - Ws;
        if (W && kb && (u32)l >= Ws) {
            u32 co = (u32)l - Ws;
            u64 p = 0ull;
            for (int r = 0; r < 64; ++r)
                p |= buf[cur][(size_t)r * W + co] & (0ull - ((kb >> r) & 1ull));
            remv |= p;
        }
        // ---- drain chunk B+1's DMAs (chain+fold time was available) ----
        if (B < 63) {
            __builtin_amdgcn_s_waitcnt(0x0F70);   // vmcnt(0)
            asm volatile("" ::: "memory");
        }
    }
    // epilogue: lane l writes final-score column of chunk l
    for (int r = 0; r < 64; ++r) {
        int i = l * 64 + r;
        float s = sc[i];
        out[(size_t)i * 25 + 24] = ((keep >> r) & 1ull) ? s : 0.0f;
    }
}

extern "C" void kernel_launch(void* const* d_in, const int* in_sizes, int n_in,
                              void* d_out, int out_size, void* d_ws, size_t ws_size,
                              hipStream_t stream) {
    const float* anchors = (const float*)d_in[0];
    const float* psm_v   = (const float*)d_in[1];
    const float* rm_v    = (const float*)d_in[2];
    const float* psm_i   = (const float*)d_in[3];
    const float* rm_i    = (const float*)d_in[4];
    const float* tproj   = (const float*)d_in[5];
    const float* tego    = (const float*)d_in[6];
    float* out = (float*)d_out;
    char* ws = (char*)d_ws;

    u32*    keys    = (u32*)(ws + OFF_KEYS);
    u64*    mask    = (u64*)(ws + OFF_KEYS);    // reuse after keys consumed
    u32*    ghist   = (u32*)(ws + OFF_GHIST);
    u32*    ghist2  = (u32*)(ws + OFF_GHIST2);
    u32*    cnt     = (u32*)(ws + OFF_CNT);
    u64*    validm  = (u64*)(ws + OFF_VALIDM);
    u64*    cand    = (u64*)(ws + OFF_CAND);
    float4* stand   = (float4*)(ws + OFF_STAND);   // overlays cand (sequential-safe)
    u32*    sel_idx = (u32*)(ws + OFF_SELIDX);
    float*  sel_sc  = (float*)(ws + OFF_SELSC);
    u64*    tdiag   = (u64*)(ws + OFF_TDIAG);

    hipMemsetAsync(ws + OFF_GHIST, 0, ZERO_BYTES, stream);
    k_keys   <<<NT / 1024, 1024, 0, stream>>>(psm_v, psm_i, keys, ghist);
    k_hist2  <<<NT / 1024, 1024, 0, stream>>>(ghist, keys, ghist2);
    k_collect<<<NT / 1024, 1024, 0, stream>>>(ghist, ghist2, keys, cand, cnt);
    k_rank   <<<32, 256, 0, stream>>>(cand, cnt, sel_idx);
    k_boxes  <<<TOPK / 256, 256, 0, stream>>>(anchors, psm_v, psm_i, rm_v, rm_i,
                                              tproj, tego, sel_idx, sel_sc, out,
                                              stand, validm);
    k_mask   <<<1024 + 16, 256, 0, stream>>>(stand, mask, tdiag);
    k_nms    <<<1, 64, 0, stream>>>(mask, tdiag, validm, sel_sc, out);
}

// Round 14
// 361.026 us; speedup vs baseline: 1.0465x; 1.0465x over previous
//
#include <hip/hip_runtime.h>
#include <stdint.h>

typedef unsigned int u32;
typedef unsigned long long u64;

#define HH 256
#define WW 512
#define HW (HH*WW)          // 131072
#define N2 (2*HW)           // 262144 per branch
#define NT (2*N2)           // 524288 total boxes
#define TOPK 4096
#define SCORE_THR 0.2f
#define NMS_THR 0.15f

// ---- workspace layout (bytes) ----
// [0, 2MB)  keys -> reused as NMS mask (4096*64 u64 = 2 MB exactly)
#define OFF_KEYS   0ull
#define OFF_GHIST  ((size_t)NT*4)                  // u32[1024] = 4 KB @ 2,097,152
#define OFF_GHIST2 (OFF_GHIST + 4096)              // u32[1024] = 4 KB
#define OFF_CNT    (OFF_GHIST2 + 4096)             // u32 (+pad 16)
#define OFF_VALIDM (OFF_CNT + 16)                  // u64[64] = 512 B
#define OFF_CAND   (OFF_VALIDM + 512)              // u64[8192] = 64 KB
#define OFF_STAND  OFF_CAND                        // float4[4096] overlays cand
#define OFF_SELIDX (OFF_CAND + 65536)              // u32[4096]
#define OFF_SELSC  (OFF_SELIDX + (size_t)TOPK*4)   // f32[4096]
#define OFF_TDIAG  (OFF_SELSC + (size_t)TOPK*4)    // u64[4096] = 32 KB
// end = 2,236,944 B < 2,261,008 proven in R6/R8
#define ZERO_BYTES (4096 + 4096 + 16)              // ghist + ghist2 + cnt

// orderable key for float (descending sortable as unsigned)
__device__ __forceinline__ u32 f2ord(float f) {
    u32 b = __float_as_uint(f);
    return (b & 0x80000000u) ? ~b : (b | 0x80000000u);
}

// ---------------- K1: scores -> keys + per-block LDS hist1 -> global -------
__global__ void __launch_bounds__(1024) k_keys(const float* __restrict__ psm_v,
                                               const float* __restrict__ psm_i,
                                               u32* __restrict__ keys,
                                               u32* __restrict__ ghist) {
    __shared__ u32 lh[1024];
    int t = threadIdx.x;
    lh[t] = 0;
    __syncthreads();
    int n = blockIdx.x * 1024 + t;
    int br = n >> 18;
    int m  = n & (N2 - 1);
    int a  = m & 1;
    int hw = m >> 1;
    const float* psm = br ? psm_i : psm_v;
    float x = psm[a * HW + hw];
    float s = 1.0f / (1.0f + __builtin_expf(-x));   // mirror ref f32 sigmoid
    u32 key = 0u;
    if (s > SCORE_THR) key = f2ord(s);
    keys[n] = key;
    if (key) atomicAdd(&lh[key >> 22], 1u);
    __syncthreads();
    u32 c = lh[t];
    if (c) atomicAdd(&ghist[t], c);
}

// Wave-0 suffix-scan pivot over a 1024-entry count array (16 entries/lane).
__device__ __forceinline__ void pivot1024(const u32* __restrict__ arr, u32 target,
                                          u32* out_bin, u32* out_next, int l) {
    u32 h[16], loc[16];
#pragma unroll
    for (int j = 0; j < 16; ++j) h[j] = arr[l * 16 + j];
    loc[15] = h[15];
#pragma unroll
    for (int j = 14; j >= 0; --j) loc[j] = loc[j + 1] + h[j];
    u32 T = loc[0];
    u32 incl = T;
#pragma unroll
    for (int d = 1; d < 64; d <<= 1) {
        u32 v = __shfl_down(incl, d);
        if (l + d < 64) incl += v;
    }
    u32 E = incl - T;                      // sum over lanes > l
#pragma unroll
    for (int j = 0; j < 16; ++j) {
        u32 S  = loc[j] + E;
        u32 Sn = (j < 15 ? loc[j + 1] : 0u) + E;
        if (S >= target && Sn < target) {
            *out_bin = (u32)(l * 16 + j);
            *out_next = Sn;
        }
    }
}

// ---------------- K2: hist2 over key>>12 within pivot-1 bin (512 blocks) ----
__global__ void __launch_bounds__(1024) k_hist2(const u32* __restrict__ ghist,
                                                const u32* __restrict__ keys,
                                                u32* __restrict__ ghist2) {
    __shared__ u32 lh[1024];
    __shared__ u32 b1_sh;
    int tid = threadIdx.x;
    lh[tid] = 0;
    if (tid < 64) {
        u32 bin = 0xFFFFFFFFu, nxt = 0;
        pivot1024(ghist, (u32)TOPK, &bin, &nxt, tid);
        if (bin != 0xFFFFFFFFu) b1_sh = bin;    // winner-lane writes
    }
    __syncthreads();
    u32 b1 = b1_sh;
    int n = blockIdx.x * 1024 + tid;
    u32 key = keys[n];
    if ((key >> 22) == b1) atomicAdd(&lh[(key >> 12) & 1023u], 1u);
    __syncthreads();
    u32 c = lh[tid];
    if (c) atomicAdd(&ghist2[tid], c);
}

// ---------------- K3: compact at 20-bit cut (512 blocks) --------------------
__global__ void __launch_bounds__(1024) k_collect(const u32* __restrict__ ghist,
                                                  const u32* __restrict__ ghist2,
                                                  const u32* __restrict__ keys,
                                                  u64* __restrict__ cand,
                                                  u32* __restrict__ cnt) {
    __shared__ u32 b1_sh, t2_sh, b2_sh;
    int tid = threadIdx.x;
    if (tid < 64) {
        u32 bin = 0xFFFFFFFFu, nxt = 0;
        pivot1024(ghist, (u32)TOPK, &bin, &nxt, tid);
        if (bin != 0xFFFFFFFFu) { b1_sh = bin; t2_sh = (u32)TOPK - nxt; }
    }
    __syncthreads();
    if (tid < 64) {
        u32 bin = 0xFFFFFFFFu, nxt = 0;
        pivot1024(ghist2, t2_sh, &bin, &nxt, tid);
        if (bin != 0xFFFFFFFFu) b2_sh = bin;
    }
    __syncthreads();
    u32 thr20 = (b1_sh << 10) | b2_sh;
    int n = blockIdx.x * 1024 + tid;
    u32 key = keys[n];
    if ((key >> 12) >= thr20) {
        u32 pos = atomicAdd(cnt, 1u);
        if (pos < 8192u)
            cand[pos] = ((u64)key << 32) | (u64)(u32)(~(u32)n);
    }
}

// ---------------- K4: rank-by-counting selection ----------------------------
__global__ void __launch_bounds__(256) k_rank(const u64* __restrict__ cand,
                                              const u32* __restrict__ cnt,
                                              u32* __restrict__ sel_idx) {
    __shared__ u64 tile[1024];
    int tid = threadIdx.x;
    int i = blockIdx.x * 256 + tid;
    u32 c = *cnt;
    if (c > 8192u) c = 8192u;
    u64 my = (i < (int)c) ? cand[i] : 0ull;
    u32 rank = 0;
    for (u32 base = 0; base < c; base += 1024) {
#pragma unroll
        for (int k = 0; k < 4; ++k) {
            u32 idx = base + tid + k * 256;
            tile[tid + k * 256] = (idx < c) ? cand[idx] : 0ull;
        }
        __syncthreads();
        u32 lim = (c - base < 1024u) ? (c - base) : 1024u;
#pragma unroll 4
        for (u32 k = 0; k < lim; ++k) rank += (tile[k] > my) ? 1u : 0u;
        __syncthreads();
    }
    if (i < (int)c && rank < (u32)TOPK)
        sel_idx[rank] = ~((u32)(my & 0xFFFFFFFFull));
}

// ---------------- box math helpers (mirror the jax reference) ---------------
__device__ __forceinline__ void box_corners(const float b[7], float cx[8], float cy[8], float cz[8]) {
    const float sx[8] = {0.5f,0.5f,-0.5f,-0.5f,0.5f,0.5f,-0.5f,-0.5f};
    const float sy[8] = {0.5f,-0.5f,-0.5f,0.5f,0.5f,-0.5f,-0.5f,0.5f};
    const float sz[8] = {-0.5f,-0.5f,-0.5f,-0.5f,0.5f,0.5f,0.5f,0.5f};
    float c = __builtin_cosf(b[6]), s = __builtin_sinf(b[6]);
#pragma unroll
    for (int k = 0; k < 8; k++) {
        float x = b[5] * sx[k], y = b[4] * sy[k], z = b[3] * sz[k];
        cx[k] = x * c - y * s + b[0];
        cy[k] = x * s + y * c + b[1];
        cz[k] = z + b[2];
    }
}

__device__ __forceinline__ void proj_T(const float* __restrict__ T, float cx[8], float cy[8], float cz[8]) {
#pragma unroll
    for (int k = 0; k < 8; k++) {
        float x = cx[k], y = cy[k], z = cz[k];
        cx[k] = T[0] * x + T[1] * y + T[2]  * z + T[3];
        cy[k] = T[4] * x + T[5] * y + T[6]  * z + T[7];
        cz[k] = T[8] * x + T[9] * y + T[10] * z + T[11];
    }
}

__device__ __forceinline__ void corner_to_center(const float cx[8], const float cy[8], const float cz[8], float b[7]) {
    float mx = 0.f, my = 0.f, mz = 0.f;
#pragma unroll
    for (int k = 0; k < 8; k++) { mx += cx[k]; my += cy[k]; mz += cz[k]; }
    mx *= 0.125f; my *= 0.125f; mz *= 0.125f;
    float htop = (cz[4] + cz[5] + cz[6] + cz[7]) * 0.25f;
    float hbot = (cz[0] + cz[1] + cz[2] + cz[3]) * 0.25f;
    const int lA[4] = {0,1,4,5}, lB[4] = {3,2,7,6};
    const int wA[4] = {0,3,4,7}, wB[4] = {1,2,5,6};
    float l = 0.f, w = 0.f, dx = 0.f, dy = 0.f;
#pragma unroll
    for (int i = 0; i < 4; i++) {
        float ax = cx[lA[i]] - cx[lB[i]];
        float ay = cy[lA[i]] - cy[lB[i]];
        l += __builtin_sqrtf(ax * ax + ay * ay);
        dx += ax; dy += ay;
    }
#pragma unroll
    for (int i = 0; i < 4; i++) {
        float ax = cx[wA[i]] - cx[wB[i]];
        float ay = cy[wA[i]] - cy[wB[i]];
        w += __builtin_sqrtf(ax * ax + ay * ay);
    }
    b[0] = mx; b[1] = my; b[2] = mz;
    b[3] = htop - hbot;
    b[4] = w * 0.25f;
    b[5] = l * 0.25f;
    b[6] = atan2f(dy, dx);
}

// ---------------- K5: decode boxes -> out corners + standup + validm --------
__global__ void __launch_bounds__(256) k_boxes(const float* __restrict__ anchors,
                                               const float* __restrict__ psm_v,
                                               const float* __restrict__ psm_i,
                                               const float* __restrict__ rm_v,
                                               const float* __restrict__ rm_i,
                                               const float* __restrict__ tproj,
                                               const float* __restrict__ tego,
                                               const u32* __restrict__ sel_idx,
                                               float* __restrict__ sel_sc,
                                               float* __restrict__ out,
                                               float4* __restrict__ stand,
                                               u64* __restrict__ validm) {
    int k = blockIdx.x * blockDim.x + threadIdx.x;
    if (k >= TOPK) return;
    int n = (int)(sel_idx[k] & (u32)(NT - 1));
    int br = n >> 18;
    int m  = n & (N2 - 1);
    int a  = m & 1;
    int hw = m >> 1;

    const float* psm = br ? psm_i : psm_v;
    float xs = psm[a * HW + hw];
    float s  = 1.0f / (1.0f + __builtin_expf(-xs));
    sel_sc[k] = (s > SCORE_THR) ? s : -1.0f;
    u64 vbits = __ballot(s > SCORE_THR);
    if ((threadIdx.x & 63) == 0) validm[k >> 6] = vbits;   // one word per wave

    const float* rm = br ? rm_i : rm_v;
    float d[7];
#pragma unroll
    for (int j = 0; j < 7; j++) d[j] = rm[(a * 7 + j) * HW + hw];
    const float* anc = anchors + (size_t)m * 7;
    float a0 = anc[0], a1 = anc[1], a2 = anc[2], a3 = anc[3], a4 = anc[4], a5 = anc[5], a6 = anc[6];
    float ad = __builtin_sqrtf(a4 * a4 + a5 * a5);
    float b[7];
    b[0] = d[0] * ad + a0;
    b[1] = d[1] * ad + a1;
    b[2] = d[2] * a3 + a2;
    b[3] = __builtin_expf(d[3]) * a3;
    b[4] = __builtin_expf(d[4]) * a4;
    b[5] = __builtin_expf(d[5]) * a5;
    b[6] = d[6] + a6;

    if (br) {  // infrared branch: corners -> t_proj -> back to center form
        float cx[8], cy[8], cz[8];
        box_corners(b, cx, cy, cz);
        proj_T(tproj, cx, cy, cz);
        corner_to_center(cx, cy, cz, b);
    }

    float cx[8], cy[8], cz[8];
    box_corners(b, cx, cy, cz);
    proj_T(tego, cx, cy, cz);

    float mnx = cx[0], mny = cy[0], mxx = cx[0], mxy = cy[0];
#pragma unroll
    for (int c = 0; c < 8; c++) {
        out[(size_t)k * 25 + c * 3 + 0] = cx[c];
        out[(size_t)k * 25 + c * 3 + 1] = cy[c];
        out[(size_t)k * 25 + c * 3 + 2] = cz[c];
        mnx = fminf(mnx, cx[c]); mny = fminf(mny, cy[c]);
        mxx = fmaxf(mxx, cx[c]); mxy = fmaxf(mxy, cy[c]);
    }
    stand[k] = make_float4(mnx, mny, mxx, mxy);
}

// ---------------- K6: suppression bitmask + fused transposed-diag -----------
__global__ void __launch_bounds__(256) k_mask(const float4* __restrict__ stand,
                                              u64* __restrict__ mask,
                                              u64* __restrict__ tdiag) {
    int bid = blockIdx.x;
    if (bid < 1024) {
        int i = bid * 4 + (threadIdx.x >> 6);
        int t = threadIdx.x & 63;
        int w0 = i >> 6;                    // chunks below diagonal are all-zero
        float4 bi = stand[i];
        float areai = (bi.z - bi.x) * (bi.w - bi.y);
        u64 myword = 0ull;
        for (int w = w0; w < 64; ++w) {
            int j = w * 64 + t;
            float4 bj = stand[j];
            float areaj = (bj.z - bj.x) * (bj.w - bj.y);
            float ltx = fmaxf(bi.x, bj.x), lty = fmaxf(bi.y, bj.y);
            float rbx = fminf(bi.z, bj.z), rby = fminf(bi.w, bj.w);
            float iw = fmaxf(rbx - ltx, 0.0f), ih = fmaxf(rby - lty, 0.0f);
            float inter = iw * ih;
            float iou = inter / (areai + areaj - inter + 1e-6f);
            bool sup = (iou > NMS_THR) && (j > i);
            u64 bits = __ballot(sup);
            if (t == w) myword = bits;
        }
        mask[(size_t)i * 64 + t] = myword;
    } else {
        int D = (bid - 1024) * 4 + (threadIdx.x >> 6);
        int l = threadIdx.x & 63;
        float4 me = stand[D * 64 + l];
        float aream = (me.z - me.x) * (me.w - me.y);
        u64 T = 0ull;
        for (int j = 0; j < 64; ++j) {
            float4 bj = stand[D * 64 + j];           // uniform -> scalar load
            float areaj = (bj.z - bj.x) * (bj.w - bj.y);
            float ltx = fmaxf(bj.x, me.x), lty = fmaxf(bj.y, me.y);
            float rbx = fminf(bj.z, me.z), rby = fminf(bj.w, me.w);
            float iw = fmaxf(rbx - ltx, 0.0f), ih = fmaxf(rby - lty, 0.0f);
            float inter = iw * ih;
            float iou = inter / (areaj + aream - inter + 1e-6f);
            bool sup = (iou > NMS_THR) && (j < l);
            T |= sup ? (1ull << j) : 0ull;
        }
        tdiag[D * 64 + l] = T;
    }
}

// ---------------- K7: single-wave NMS, depth-2 static DMA pipeline ----------
// 3 ping-pong buffers: chunk B+2 issued at iter B; s_waitcnt vmcnt(32) at
// iter END drains only B+1 (in-order completion; B+2's 32 stay in flight) ->
// every chunk's DMAs get ~2 full loop bodies of cover. All staging/fold loops
// static+unrolled (R13 showed dynamic loops cost ~2k cyc/chunk). tdiag is
// staged to LDS in the prologue; validm lives per-lane in a register; no
// global vector loads inside the loop, so vmcnt counts only DMAs.
template<int MODE>   // 0: issue B+2 & wait vmcnt(32); 1 (B=62): wait vmcnt(0); 2 (B=63): none
__device__ __forceinline__ void nms_step(int B, const u64* bufcur, u64* bufnx2,
                                         const u64* __restrict__ mask,
                                         const u64* tsh, u64 vmreg,
                                         u64& remv, u64& keep, int l) {
    if (MODE == 0) {   // stage chunk B+2 (fully static addressing)
        const u64* gb = mask + (size_t)(B + 2) * 4096;
#pragma unroll
        for (int j = 0; j < 32; ++j) {
            const u64* g = gb + (size_t)j * 128 + l * 2;
            __builtin_amdgcn_global_load_lds(
                (const __attribute__((address_space(1))) void*)g,
                (__attribute__((address_space(3))) void*)&bufnx2[(size_t)j * 128],
                16, 0, 0);
        }
        asm volatile("" ::: "memory");
    }
    // ---- chain: fixpoint on transposed words (R11-proven) ----
    u64 Tl = tsh[B * 64 + l];                         // LDS, lgkmcnt only
    u64 vm = (((u64)(u32)__builtin_amdgcn_readlane((int)(u32)(vmreg >> 32), B)) << 32)
           |   (u64)(u32)__builtin_amdgcn_readlane((int)(u32)vmreg, B);
    u64 curw = (((u64)(u32)__builtin_amdgcn_readlane((int)(u32)(remv >> 32), B)) << 32)
             |   (u64)(u32)__builtin_amdgcn_readlane((int)(u32)remv, B);
    u64 ve = vm & ~curw;
    u64 D = 0ull, P = ve;
    while (D != P) {
        u64 nD = ve & ~__ballot((Tl & P) != 0ull);
        u64 nP = ve & ~__ballot((Tl & nD) != 0ull);
        D = nD; P = nP;
    }
    u64 kb = D;
    keep = (l == B) ? kb : keep;
    // ---- fold chunk B's kept rows (resident since iter B-1's wait) ----
    u64 p = 0ull;
#pragma unroll
    for (int r = 0; r < 64; ++r)
        p |= bufcur[r * 64 + l] & (0ull - ((kb >> r) & 1ull));
    remv |= p;
    // ---- pipeline wait: drain B+1 only (B+2 stays in flight) ----
    if (MODE == 0) {
        __builtin_amdgcn_s_waitcnt(0x8F70);   // vmcnt(32)
        asm volatile("" ::: "memory");
    } else if (MODE == 1) {
        __builtin_amdgcn_s_waitcnt(0x0F70);   // vmcnt(0): drain chunk 63
        asm volatile("" ::: "memory");
    }
}

__global__ void __launch_bounds__(64) k_nms(const u64* __restrict__ mask,
                                            const u64* __restrict__ tdiag,
                                            const u64* __restrict__ validm,
                                            const float* __restrict__ sc,
                                            float* __restrict__ out) {
    __shared__ u64 buf[3][4096];   // 96 KB ping-pong-pong
    __shared__ u64 tsh[4096];      // 32 KB staged tdiag  (total 128 KB < 160 KB)
    int l = threadIdx.x;
    u64 remv = 0ull;
    u64 keep = 0ull;
    u64 vmreg = validm[l];         // per-lane; issued before all DMAs
    // prologue: stage tdiag, chunk 0, chunk 1
#pragma unroll
    for (int j = 0; j < 32; ++j) {
        const u64* g = tdiag + (size_t)j * 128 + l * 2;
        __builtin_amdgcn_global_load_lds(
            (const __attribute__((address_space(1))) void*)g,
            (__attribute__((address_space(3))) void*)&tsh[(size_t)j * 128], 16, 0, 0);
    }
#pragma unroll
    for (int j = 0; j < 32; ++j) {
        const u64* g = mask + (size_t)j * 128 + l * 2;
        __builtin_amdgcn_global_load_lds(
            (const __attribute__((address_space(1))) void*)g,
            (__attribute__((address_space(3))) void*)&buf[0][(size_t)j * 128], 16, 0, 0);
    }
#pragma unroll
    for (int j = 0; j < 32; ++j) {
        const u64* g = mask + (size_t)4096 + (size_t)j * 128 + l * 2;
        __builtin_amdgcn_global_load_lds(
            (const __attribute__((address_space(1))) void*)g,
            (__attribute__((address_space(3))) void*)&buf[1][(size_t)j * 128], 16, 0, 0);
    }
    __builtin_amdgcn_s_waitcnt(0x8F70);   // vmcnt(32): tdiag+chunk0 done, chunk1 in flight
    asm volatile("" ::: "memory");
    // B = 0..59 in 20 triples (B%3 compile-time per call site)
    for (int t = 0; t < 20; ++t) {
        int B = t * 3;
        nms_step<0>(B,     buf[0], buf[2], mask, tsh, vmreg, remv, keep, l);
        nms_step<0>(B + 1, buf[1], buf[0], mask, tsh, vmreg, remv, keep, l);
        nms_step<0>(B + 2, buf[2], buf[1], mask, tsh, vmreg, remv, keep, l);
    }
    nms_step<0>(60, buf[0], buf[2], mask, tsh, vmreg, remv, keep, l);  // issues 62
    nms_step<0>(61, buf[1], buf[0], mask, tsh, vmreg, remv, keep, l);  // issues 63
    nms_step<1>(62, buf[2], buf[1], mask, tsh, vmreg, remv, keep, l);  // wait vmcnt(0)
    nms_step<2>(63, buf[0], buf[1], mask, tsh, vmreg, remv, keep, l);  // no issue/wait
    // epilogue: lane l writes final-score column of chunk l
    for (int r = 0; r < 64; ++r) {
        int i = l * 64 + r;
        float s = sc[i];
        out[(size_t)i * 25 + 24] = ((keep >> r) & 1ull) ? s : 0.0f;
    }
}

extern "C" void kernel_launch(void* const* d_in, const int* in_sizes, int n_in,
                              void* d_out, int out_size, void* d_ws, size_t ws_size,
                              hipStream_t stream) {
    const float* anchors = (const float*)d_in[0];
    const float* psm_v   = (const float*)d_in[1];
    const float* rm_v    = (const float*)d_in[2];
    const float* psm_i   = (const float*)d_in[3];
    const float* rm_i    = (const float*)d_in[4];
    const float* tproj   = (const float*)d_in[5];
    const float* tego    = (const float*)d_in[6];
    float* out = (float*)d_out;
    char* ws = (char*)d_ws;

    u32*    keys    = (u32*)(ws + OFF_KEYS);
    u64*    mask    = (u64*)(ws + OFF_KEYS);    // reuse after keys consumed
    u32*    ghist   = (u32*)(ws + OFF_GHIST);
    u32*    ghist2  = (u32*)(ws + OFF_GHIST2);
    u32*    cnt     = (u32*)(ws + OFF_CNT);
    u64*    validm  = (u64*)(ws + OFF_VALIDM);
    u64*    cand    = (u64*)(ws + OFF_CAND);
    float4* stand   = (float4*)(ws + OFF_STAND);   // overlays cand (sequential-safe)
    u32*    sel_idx = (u32*)(ws + OFF_SELIDX);
    float*  sel_sc  = (float*)(ws + OFF_SELSC);
    u64*    tdiag   = (u64*)(ws + OFF_TDIAG);

    hipMemsetAsync(ws + OFF_GHIST, 0, ZERO_BYTES, stream);
    k_keys   <<<NT / 1024, 1024, 0, stream>>>(psm_v, psm_i, keys, ghist);
    k_hist2  <<<NT / 1024, 1024, 0, stream>>>(ghist, keys, ghist2);
    k_collect<<<NT / 1024, 1024, 0, stream>>>(ghist, ghist2, keys, cand, cnt);
    k_rank   <<<32, 256, 0, stream>>>(cand, cnt, sel_idx);
    k_boxes  <<<TOPK / 256, 256, 0, stream>>>(anchors, psm_v, psm_i, rm_v, rm_i,
                                              tproj, tego, sel_idx, sel_sc, out,
                                              stand, validm);
    k_mask   <<<1024 + 16, 256, 0, stream>>>(stand, mask, tdiag);
    k_nms    <<<1, 64, 0, stream>>>(mask, tdiag, validm, sel_sc, out);
}